// Round 4
// baseline (295.620 us; speedup 1.0000x reference)
//
#include <hip/hip_runtime.h>
#include <stdint.h>

// Recall over [B=32, F=512, T=2048]:
//   p_adj[b,f,t] = predicted[b, f==0?1:f, t==0?1:t]
//   out = sum(p_adj * (gt!=0)) / count(gt!=0), or 0 if count==0.
//
// R4: force memory-level parallelism with inline-asm loads. R2/R3 showed the
// compiler collapses any source-level prefetch pack to ~2 loads in flight
// (VGPR=36, 116us, duration independent of HBM vs L3 sourcing => pure
// latency-bound). Here each thread issues 16 global_load_dwordx4 via volatile
// asm (program-order preserved), then consumes with staged s_waitcnt
// vmcnt(14-2k) asms that carry the consumed registers as "+v" operands.

constexpr int B_ = 32;
constexpr int F_ = 512;
constexpr int T_ = 2048;
constexpr long long NTOT = (long long)B_ * F_ * T_;   // 2^25
constexpr int NQ      = (int)(NTOT >> 2);             // 8,388,608 quads
constexpr int BLK     = 256;
constexpr int NBLK    = 4096;
constexpr int PER_THR = 8;                            // NQ / (BLK*NBLK)
static_assert((long long)BLK * NBLK * PER_THR == NQ, "exact cover");

constexpr int EDGE_ITEMS = B_ * T_ + B_ * F_;         // 81,920
constexpr int EDGE_BLKS  = EDGE_ITEMS / BLK;          // 320

typedef float vf4 __attribute__((ext_vector_type(4)));
typedef int   vi4 __attribute__((ext_vector_type(4)));

// ---------------- block reduction helper ----------------
__device__ __forceinline__ void block_reduce(float& s, int& c) {
    #pragma unroll
    for (int off = 32; off > 0; off >>= 1) {
        s += __shfl_down(s, off, 64);
        c += __shfl_down(c, off, 64);
    }
    __shared__ float ss[4];
    __shared__ int   sc[4];
    int lane = threadIdx.x & 63, wave = threadIdx.x >> 6;
    if (lane == 0) { ss[wave] = s; sc[wave] = c; }
    __syncthreads();
    if (threadIdx.x == 0) {
        s = ss[0] + ss[1] + ss[2] + ss[3];
        c = sc[0] + sc[1] + sc[2] + sc[3];
    }
}

// ---------------- main branchless masked sum ----------------
__global__ __launch_bounds__(256, 1) void recall_main(
    const float* __restrict__ pred,
    const int* __restrict__ gt,
    float* __restrict__ bsum,
    unsigned int* __restrict__ bcnt)
{
    const unsigned tid    = blockIdx.x * BLK + threadIdx.x;
    const unsigned STRIDE = (unsigned)BLK * NBLK;      // 1,048,576 quads

    vf4 p[PER_THR];
    vi4 g[PER_THR];

    // Issue all 16 loads back-to-back. volatile asm keeps program order;
    // the compiler cannot sink these into the consume chain.
    #pragma unroll
    for (int k = 0; k < PER_THR; ++k) {
        uint64_t pa = (uint64_t)(pred) + ((uint64_t)tid + (uint64_t)k * STRIDE) * 16u;
        uint64_t ga = (uint64_t)(gt)   + ((uint64_t)tid + (uint64_t)k * STRIDE) * 16u;
        asm volatile("global_load_dwordx4 %0, %1, off" : "=v"(p[k]) : "v"(pa));
        asm volatile("global_load_dwordx4 %0, %1, off" : "=v"(g[k]) : "v"(ga));
    }

    float lsum = 0.f;
    int   lcnt = 0;
    // Staged consumption: pair k is loads (2k, 2k+1); waiting until only
    // 14-2k remain outstanding guarantees pair k has landed (vmcnt retires
    // in issue order). "+v" ties the data to the wait so the consumer
    // cannot be scheduled above it.
    #pragma unroll
    for (int k = 0; k < PER_THR; ++k) {
        asm volatile("s_waitcnt vmcnt(%2)"
                     : "+v"(p[k]), "+v"(g[k])
                     : "n"(14 - 2 * k));
        lcnt += (g[k].x != 0) + (g[k].y != 0) + (g[k].z != 0) + (g[k].w != 0);
        lsum += (g[k].x ? p[k].x : 0.f);
        lsum += (g[k].y ? p[k].y : 0.f);
        lsum += (g[k].z ? p[k].z : 0.f);
        lsum += (g[k].w ? p[k].w : 0.f);
    }

    block_reduce(lsum, lcnt);
    if (threadIdx.x == 0) {
        bsum[blockIdx.x] = lsum;
        bcnt[blockIdx.x] = (unsigned int)lcnt;
    }
}

// ---------------- edge-remap correction ----------------
// Items [0, B*T):          f==0 row  (all t; remap f->1, t->max(t,1))
// Items [B*T, B*T + B*F):  t==0 col, f>=1 only (remap t->1); f==0 cell
// is covered by the first range.
__global__ __launch_bounds__(256) void recall_edge(
    const float* __restrict__ pred,
    const int* __restrict__ gt,
    float* __restrict__ csum)
{
    unsigned idx = blockIdx.x * BLK + threadIdx.x;
    float corr = 0.f;
    if (idx < (unsigned)(B_ * T_)) {
        unsigned b = idx >> 11, t = idx & (T_ - 1);
        unsigned raw = (b << 20) | t;
        unsigned tp  = (t == 0u) ? 1u : t;
        unsigned adj = (b << 20) | (1u << 11) | tp;
        if (gt[raw]) corr = pred[adj] - pred[raw];
    } else {
        unsigned i2 = idx - (unsigned)(B_ * T_);
        unsigned b = i2 >> 9, f = i2 & (F_ - 1);
        if (f != 0u) {
            unsigned raw = (b << 20) | (f << 11);
            if (gt[raw]) corr = pred[raw + 1] - pred[raw];
        }
    }
    int dummy = 0;
    block_reduce(corr, dummy);
    if (threadIdx.x == 0) csum[blockIdx.x] = corr;
}

// ---------------- finalize ----------------
__global__ __launch_bounds__(256) void recall_fin(
    const float* __restrict__ bsum,
    const unsigned int* __restrict__ bcnt,
    const float* __restrict__ csum,
    float* __restrict__ out)
{
    float s = 0.f;
    int   c = 0;
    for (int j = threadIdx.x; j < NBLK; j += BLK) {
        s += bsum[j];
        c += (int)bcnt[j];
    }
    for (int j = threadIdx.x; j < EDGE_BLKS; j += BLK) s += csum[j];

    block_reduce(s, c);
    if (threadIdx.x == 0)
        out[0] = (c > 0) ? (s / (float)c) : 0.0f;
}

extern "C" void kernel_launch(void* const* d_in, const int* in_sizes, int n_in,
                              void* d_out, int out_size, void* d_ws, size_t ws_size,
                              hipStream_t stream)
{
    const float* pred = (const float*)d_in[0];
    const int*   gt   = (const int*)d_in[1];
    float*       out  = (float*)d_out;

    float*        bsum = (float*)d_ws;
    unsigned int* bcnt = (unsigned int*)((char*)d_ws + NBLK * sizeof(float));
    float*        csum = (float*)((char*)d_ws + 2 * NBLK * sizeof(float));

    recall_main<<<NBLK, BLK, 0, stream>>>(pred, gt, bsum, bcnt);
    recall_edge<<<EDGE_BLKS, BLK, 0, stream>>>(pred, gt, csum);
    recall_fin<<<1, BLK, 0, stream>>>(bsum, bcnt, csum, out);
}

// Round 5
// 279.979 us; speedup vs baseline: 1.0559x; 1.0559x over previous
//
#include <hip/hip_runtime.h>

// Recall over [B=32, F=512, T=2048]:
//   p_adj[b,f,t] = predicted[b, f==0?1:f, t==0?1:t]
//   out = sum(p_adj * (gt!=0)) / count(gt!=0), or 0 if count==0.
//
// R5: contiguous tiling. R1-R4 all used 16MB-strided per-thread access;
// measurements showed ~271 cy per vmem instruction per CU, independent of
// HBM-vs-L3 sourcing => serialized address-translation (UTCL1 thrash), not
// bandwidth. Here block b covers a contiguous 32KB chunk, wave w a contiguous
// 8KB chunk, each wave-instruction a coalesced contiguous 1KB:
//   quad = b*2048 + w*512 + k*64 + lane.
// Kernel structure otherwise identical to R2 for clean attribution.

constexpr int B_ = 32;
constexpr int F_ = 512;
constexpr int T_ = 2048;
constexpr long long NTOT = (long long)B_ * F_ * T_;   // 2^25
constexpr int NQ      = (int)(NTOT >> 2);             // 8,388,608 quads
constexpr int BLK     = 256;
constexpr int NBLK    = 4096;
constexpr int PER_THR = 8;                            // NQ / (BLK*NBLK)
constexpr int QPB     = NQ / NBLK;                    // 2048 quads per block
constexpr int QPW     = QPB / 4;                      // 512 quads per wave
static_assert((long long)BLK * NBLK * PER_THR == NQ, "exact cover");

constexpr int EDGE_ITEMS = B_ * T_ + B_ * F_;         // 81,920
constexpr int EDGE_BLKS  = EDGE_ITEMS / BLK;          // 320

// ---------------- block reduction helper ----------------
__device__ __forceinline__ void block_reduce(float& s, int& c) {
    #pragma unroll
    for (int off = 32; off > 0; off >>= 1) {
        s += __shfl_down(s, off, 64);
        c += __shfl_down(c, off, 64);
    }
    __shared__ float ss[4];
    __shared__ int   sc[4];
    int lane = threadIdx.x & 63, wave = threadIdx.x >> 6;
    if (lane == 0) { ss[wave] = s; sc[wave] = c; }
    __syncthreads();
    if (threadIdx.x == 0) {
        s = ss[0] + ss[1] + ss[2] + ss[3];
        c = sc[0] + sc[1] + sc[2] + sc[3];
    }
}

// ---------------- main branchless masked sum ----------------
__global__ __launch_bounds__(256) void recall_main(
    const float4* __restrict__ p4,
    const int4* __restrict__ g4,
    float* __restrict__ bsum,
    unsigned int* __restrict__ bcnt)
{
    const unsigned lane = threadIdx.x & 63;
    const unsigned wave = threadIdx.x >> 6;
    // Contiguous: block covers [blockIdx.x*QPB, +QPB), wave covers QPW of it,
    // instruction k is a coalesced 1KB wave access.
    const size_t base = (size_t)blockIdx.x * QPB + (size_t)wave * QPW + lane;

    int4   g[PER_THR];
    float4 p[PER_THR];
    #pragma unroll
    for (int k = 0; k < PER_THR; ++k) {
        size_t q = base + (size_t)k * 64;
        g[k] = g4[q];
        p[k] = p4[q];
    }

    float lsum = 0.f;
    int   lcnt = 0;
    #pragma unroll
    for (int k = 0; k < PER_THR; ++k) {
        lcnt += (g[k].x != 0) + (g[k].y != 0) + (g[k].z != 0) + (g[k].w != 0);
        lsum += (g[k].x ? p[k].x : 0.f);
        lsum += (g[k].y ? p[k].y : 0.f);
        lsum += (g[k].z ? p[k].z : 0.f);
        lsum += (g[k].w ? p[k].w : 0.f);
    }

    block_reduce(lsum, lcnt);
    if (threadIdx.x == 0) {
        bsum[blockIdx.x] = lsum;
        bcnt[blockIdx.x] = (unsigned int)lcnt;
    }
}

// ---------------- edge-remap correction ----------------
// Items [0, B*T):          f==0 row  (all t; remap f->1, t->max(t,1))
// Items [B*T, B*T + B*F):  t==0 col, f>=1 only (remap t->1); f==0 cell
// is covered by the first range.
__global__ __launch_bounds__(256) void recall_edge(
    const float* __restrict__ pred,
    const int* __restrict__ gt,
    float* __restrict__ csum)
{
    unsigned idx = blockIdx.x * BLK + threadIdx.x;
    float corr = 0.f;
    if (idx < (unsigned)(B_ * T_)) {
        unsigned b = idx >> 11, t = idx & (T_ - 1);
        unsigned raw = (b << 20) | t;
        unsigned tp  = (t == 0u) ? 1u : t;
        unsigned adj = (b << 20) | (1u << 11) | tp;
        if (gt[raw]) corr = pred[adj] - pred[raw];
    } else {
        unsigned i2 = idx - (unsigned)(B_ * T_);
        unsigned b = i2 >> 9, f = i2 & (F_ - 1);
        if (f != 0u) {
            unsigned raw = (b << 20) | (f << 11);
            if (gt[raw]) corr = pred[raw + 1] - pred[raw];
        }
    }
    int dummy = 0;
    block_reduce(corr, dummy);
    if (threadIdx.x == 0) csum[blockIdx.x] = corr;
}

// ---------------- finalize ----------------
__global__ __launch_bounds__(256) void recall_fin(
    const float* __restrict__ bsum,
    const unsigned int* __restrict__ bcnt,
    const float* __restrict__ csum,
    float* __restrict__ out)
{
    float s = 0.f;
    int   c = 0;
    for (int j = threadIdx.x; j < NBLK; j += BLK) {
        s += bsum[j];
        c += (int)bcnt[j];
    }
    for (int j = threadIdx.x; j < EDGE_BLKS; j += BLK) s += csum[j];

    block_reduce(s, c);
    if (threadIdx.x == 0)
        out[0] = (c > 0) ? (s / (float)c) : 0.0f;
}

extern "C" void kernel_launch(void* const* d_in, const int* in_sizes, int n_in,
                              void* d_out, int out_size, void* d_ws, size_t ws_size,
                              hipStream_t stream)
{
    const float* pred = (const float*)d_in[0];
    const int*   gt   = (const int*)d_in[1];
    float*       out  = (float*)d_out;

    float*        bsum = (float*)d_ws;
    unsigned int* bcnt = (unsigned int*)((char*)d_ws + NBLK * sizeof(float));
    float*        csum = (float*)((char*)d_ws + 2 * NBLK * sizeof(float));

    recall_main<<<NBLK, BLK, 0, stream>>>((const float4*)pred, (const int4*)gt,
                                          bsum, bcnt);
    recall_edge<<<EDGE_BLKS, BLK, 0, stream>>>(pred, gt, csum);
    recall_fin<<<1, BLK, 0, stream>>>(bsum, bcnt, csum, out);
}